// Round 14
// baseline (306.133 us; speedup 1.0000x reference)
//
#include <hip/hip_runtime.h>
#include <hip/hip_bf16.h>

#define BB 4
#define NN 1024
#define KK 48
#define HH 128
#define EE 128
#define IN3 384
#define FF 512
#define ST 132   // LDS row stride (ushorts)

typedef __attribute__((ext_vector_type(8))) short bf16x8;
typedef __attribute__((ext_vector_type(4))) float f32x4;

#define MFMA(a, b, c) __builtin_amdgcn_mfma_f32_16x16x32_bf16((a), (b), (c), 0, 0, 0)

__device__ __forceinline__ float bf2f(ushort u) {
    union { uint i; float f; } v; v.i = ((uint)u) << 16; return v.f;
}
__device__ __forceinline__ uint cvtpk(float a, float b) {
    uint r;
    asm("v_cvt_pk_bf16_f32 %0, %1, %2" : "=v"(r) : "v"(a), "v"(b));
    return r;
}
__device__ __forceinline__ ushort f2bf1(float v) {
    return (ushort)cvtpk(v, v);
}
__device__ __forceinline__ float wsum(float x) {
    #pragma unroll
    for (int o = 32; o; o >>= 1) x += __shfl_xor(x, o, 64);
    return x;
}
// tanh-form gelu: x*z/(z+1), z = exp2(2.3022061*(x + 0.044715 x^3))
__device__ __forceinline__ float gelu_f(float x) {
    float t = x * fmaf(x * x, 0.044715f, 1.0f);
    float a = fminf(t * 2.3022061f, 50.0f);
    float z;
    asm("v_exp_f32 %0, %1" : "=v"(z) : "v"(a));
    float r;
    asm("v_rcp_f32 %0, %1" : "=v"(r) : "v"(z + 1.0f));
    return x * z * r;
}

// ---------------- Kernel 0: all-weights fp32 -> bf16 (single launch) ----------------
__global__ __launch_bounds__(256) void k_cvt8(
    const float* __restrict__ s0, const float* __restrict__ s1,
    const float* __restrict__ s2, const float* __restrict__ s3,
    const float* __restrict__ s4, const float* __restrict__ s5,
    const float* __restrict__ s6, const float* __restrict__ s7,
    ushort* __restrict__ d0, ushort* __restrict__ d1,
    ushort* __restrict__ d2, ushort* __restrict__ d3,
    ushort* __restrict__ d4, ushort* __restrict__ d5,
    ushort* __restrict__ d6, ushort* __restrict__ d7) {
    int i = blockIdx.x * 256 + threadIdx.x;
    const float* s; ushort* d; int base;
    if      (i < 12288) { s = s0; d = d0; base = 0; }
    else if (i < 16384) { s = s1; d = d1; base = 12288; }
    else if (i < 20480) { s = s2; d = d2; base = 16384; }
    else if (i < 32768) { s = s3; d = d3; base = 20480; }
    else if (i < 36864) { s = s4; d = d4; base = 32768; }
    else if (i < 40960) { s = s5; d = d5; base = 36864; }
    else if (i < 57344) { s = s6; d = d6; base = 40960; }
    else                { s = s7; d = d7; base = 57344; }
    int j = i - base;
    float4 v = ((const float4*)s)[j];
    uint2 o;
    o.x = cvtpk(v.x, v.y);
    o.y = cvtpk(v.z, v.w);
    ((uint2*)d)[j] = o;
}

// ---------------- Kernel 1: LN0 over all nodes -> ws (bf16) ----------------
__global__ __launch_bounds__(256) void k_ln0(const float* __restrict__ hV,
                                             const float* __restrict__ g,
                                             const float* __restrict__ bta,
                                             ushort* __restrict__ out) {
    int row = blockIdx.x * 4 + (threadIdx.x >> 6);
    int l = threadIdx.x & 63;
    const float* src = hV + (size_t)row * HH;
    float x0 = src[l], x1 = src[l + 64];
    float s = wsum(x0 + x1);
    float q = wsum(x0 * x0 + x1 * x1);
    float mu = s * (1.0f / 128.0f);
    float rstd = rsqrtf(q * (1.0f / 128.0f) - mu * mu + 1e-5f);
    ushort* dst = out + (size_t)row * HH;
    dst[l]      = f2bf1((x0 - mu) * rstd * g[l]      + bta[l]);
    dst[l + 64] = f2bf1((x1 - mu) * rstd * g[l + 64] + bta[l + 64]);
}

// ---------------- Kernel 2: node message MLP, 2 nodes/block (M=96) ----------------
__global__ __launch_bounds__(256, 6) void k_node(
    const float* __restrict__ hV, const float* __restrict__ hE,
    const int* __restrict__ Eidx, const float* __restrict__ maskAtt,
    const ushort* __restrict__ W1w, const float* __restrict__ W1b,
    const ushort* __restrict__ W2w, const float* __restrict__ W2b,
    const ushort* __restrict__ W3w, const float* __restrict__ W3b,
    const float* __restrict__ resw,
    const ushort* __restrict__ hVn,   // LN0(h_V), bf16
    float* __restrict__ outHVp) {     // h_V' fp32

    __shared__ ushort buf[96 * ST];   // out1 / out2 (in-place with barriers)
    __shared__ float  sMask[96];
    __shared__ float  sCol[256];      // [2][128]

    const int t = threadIdx.x;
    const int w = t >> 6;
    const int lane = t & 63;
    const int np = blockIdx.x * 2;    // first node of the pair (b*N+n space)
    const int b  = np >> 10;
    const int r16 = lane & 15, g4 = lane >> 4;

    // edge indices for my 6 m-tiles (rows of the pair are contiguous: row = mt*16+r16)
    int myidx[6];
    #pragma unroll
    for (int mt = 0; mt < 6; mt++)
        myidx[mt] = Eidx[np * KK + mt * 16 + r16];
    if (t < 96) sMask[t] = maskAtt[np * KK + t];

    f32x4 acc[6][2];
    #pragma unroll
    for (int mt = 0; mt < 6; mt++) {
        acc[mt][0] = (f32x4){0.f, 0.f, 0.f, 0.f};
        acc[mt][1] = (f32x4){0.f, 0.f, 0.f, 0.f};
    }

    const ushort* Wp  = W1w + (w * 32 + r16) * IN3 + g4 * 8;
    const float*  hE0 = hE + (size_t)np * KK * EE;   // 96 contiguous rows

    // ---- GEMM1 section: h_E cols [128,256) (deepest latency first) ----
    #pragma unroll
    for (int kt = 0; kt < 4; kt++) {
        bf16x8 b0 = *(const bf16x8*)(Wp + 128 + kt * 32);
        bf16x8 b1 = *(const bf16x8*)(Wp + 16 * IN3 + 128 + kt * 32);
        #pragma unroll
        for (int mt = 0; mt < 6; mt++) {
            const float* p = hE0 + (size_t)(mt * 16 + r16) * EE + kt * 32 + g4 * 8;
            float4 f0 = *(const float4*)(p);
            float4 f1 = *(const float4*)(p + 4);
            union { uint u[4]; bf16x8 v; } a;
            a.u[0] = cvtpk(f0.x, f0.y); a.u[1] = cvtpk(f0.z, f0.w);
            a.u[2] = cvtpk(f1.x, f1.y); a.u[3] = cvtpk(f1.z, f1.w);
            acc[mt][0] = MFMA(a.v, b0, acc[mt][0]);
            acc[mt][1] = MFMA(a.v, b1, acc[mt][1]);
        }
    }
    // ---- GEMM1 section: neighbor LN0 cols [256,384) ----
    {
        const ushort* nb = hVn + (size_t)b * NN * HH + g4 * 8;
        #pragma unroll
        for (int kt = 0; kt < 4; kt++) {
            bf16x8 b0 = *(const bf16x8*)(Wp + 256 + kt * 32);
            bf16x8 b1 = *(const bf16x8*)(Wp + 16 * IN3 + 256 + kt * 32);
            #pragma unroll
            for (int mt = 0; mt < 6; mt++) {
                bf16x8 a = *(const bf16x8*)(nb + (size_t)myidx[mt] * HH + kt * 32);
                acc[mt][0] = MFMA(a, b0, acc[mt][0]);
                acc[mt][1] = MFMA(a, b1, acc[mt][1]);
            }
        }
    }
    // ---- GEMM1 section: self LN0 cols [0,128) (two broadcast rows) ----
    {
        const ushort* sp0 = hVn + (size_t)np * HH + g4 * 8;
        const ushort* sp1 = sp0 + HH;
        #pragma unroll
        for (int kt = 0; kt < 4; kt++) {
            bf16x8 a0 = *(const bf16x8*)(sp0 + kt * 32);
            bf16x8 a1 = *(const bf16x8*)(sp1 + kt * 32);
            bf16x8 b0 = *(const bf16x8*)(Wp + kt * 32);
            bf16x8 b1 = *(const bf16x8*)(Wp + 16 * IN3 + kt * 32);
            #pragma unroll
            for (int mt = 0; mt < 6; mt++) {
                bf16x8 a = (mt < 3) ? a0 : a1;
                acc[mt][0] = MFMA(a, b0, acc[mt][0]);
                acc[mt][1] = MFMA(a, b1, acc[mt][1]);
            }
        }
    }
    // bias + gelu -> buf (out1)
    #pragma unroll
    for (int nn = 0; nn < 2; nn++) {
        int col = w * 32 + nn * 16 + r16;
        float bb = W1b[col];
        #pragma unroll
        for (int mt = 0; mt < 6; mt++)
            #pragma unroll
            for (int r = 0; r < 4; r++)
                buf[(mt * 16 + g4 * 4 + r) * ST + col] = f2bf1(gelu_f(acc[mt][nn][r] + bb));
    }
    __syncthreads();

    // ---- GEMM2 ----
    f32x4 acc2[6][2];
    #pragma unroll
    for (int mt = 0; mt < 6; mt++) {
        acc2[mt][0] = (f32x4){0.f, 0.f, 0.f, 0.f};
        acc2[mt][1] = (f32x4){0.f, 0.f, 0.f, 0.f};
    }
    {
        const ushort* Wp2 = W2w + (w * 32 + r16) * HH + g4 * 8;
        #pragma unroll
        for (int kt = 0; kt < 4; kt++) {
            bf16x8 b0 = *(const bf16x8*)(Wp2 + kt * 32);
            bf16x8 b1 = *(const bf16x8*)(Wp2 + 16 * HH + kt * 32);
            #pragma unroll
            for (int mt = 0; mt < 6; mt++) {
                bf16x8 a = *(const bf16x8*)&buf[(mt * 16 + r16) * ST + kt * 32 + g4 * 8];
                acc2[mt][0] = MFMA(a, b0, acc2[mt][0]);
                acc2[mt][1] = MFMA(a, b1, acc2[mt][1]);
            }
        }
    }
    __syncthreads();   // all reads of out1 complete
    #pragma unroll
    for (int nn = 0; nn < 2; nn++) {
        int col = w * 32 + nn * 16 + r16;
        float bb = W2b[col];
        #pragma unroll
        for (int mt = 0; mt < 6; mt++)
            #pragma unroll
            for (int r = 0; r < 4; r++)
                buf[(mt * 16 + g4 * 4 + r) * ST + col] = f2bf1(gelu_f(acc2[mt][nn][r] + bb));
    }
    __syncthreads();

    // ---- GEMM3 + masked per-node column sum ----
    f32x4 acc3[6][2];
    #pragma unroll
    for (int mt = 0; mt < 6; mt++) {
        acc3[mt][0] = (f32x4){0.f, 0.f, 0.f, 0.f};
        acc3[mt][1] = (f32x4){0.f, 0.f, 0.f, 0.f};
    }
    {
        const ushort* Wp3 = W3w + (w * 32 + r16) * HH + g4 * 8;
        #pragma unroll
        for (int kt = 0; kt < 4; kt++) {
            bf16x8 b0 = *(const bf16x8*)(Wp3 + kt * 32);
            bf16x8 b1 = *(const bf16x8*)(Wp3 + 16 * HH + kt * 32);
            #pragma unroll
            for (int mt = 0; mt < 6; mt++) {
                bf16x8 a = *(const bf16x8*)&buf[(mt * 16 + r16) * ST + kt * 32 + g4 * 8];
                acc3[mt][0] = MFMA(a, b0, acc3[mt][0]);
                acc3[mt][1] = MFMA(a, b1, acc3[mt][1]);
            }
        }
    }
    {
        float b3a = W3b[w * 32 + r16];
        float b3b = W3b[w * 32 + 16 + r16];
        float s0a = 0.f, s0b = 0.f, s1a = 0.f, s1b = 0.f;
        #pragma unroll
        for (int mt = 0; mt < 6; mt++)
            #pragma unroll
            for (int r = 0; r < 4; r++) {
                int row = mt * 16 + g4 * 4 + r;
                float mk = sMask[row];
                float v0 = (acc3[mt][0][r] + b3a) * mk;
                float v1 = (acc3[mt][1][r] + b3b) * mk;
                if (mt < 3) { s0a += v0; s0b += v1; }
                else        { s1a += v0; s1b += v1; }
            }
        s0a += __shfl_xor(s0a, 16, 64); s0a += __shfl_xor(s0a, 32, 64);
        s0b += __shfl_xor(s0b, 16, 64); s0b += __shfl_xor(s0b, 32, 64);
        s1a += __shfl_xor(s1a, 16, 64); s1a += __shfl_xor(s1a, 32, 64);
        s1b += __shfl_xor(s1b, 16, 64); s1b += __shfl_xor(s1b, 32, 64);
        if (g4 == 0) {
            sCol[w * 32 + r16]            = s0a;
            sCol[w * 32 + 16 + r16]       = s0b;
            sCol[128 + w * 32 + r16]      = s1a;
            sCol[128 + w * 32 + 16 + r16] = s1b;
        }
    }
    __syncthreads();

    {
        float rw = resw[0];
        size_t o = (size_t)np * HH + t;    // t spans both nodes' 128 cols
        outHVp[o] = hV[o] + sCol[t] * (1.0f / 30.0f) * rw;
    }
}

// ---------------- Kernel 3: batched FFN (LN1 + Win/gelu/Wout, MFMA) ----------------
__global__ __launch_bounds__(256, 4) void k_ffn(
    const float* __restrict__ maskV,
    const float* __restrict__ ln1g, const float* __restrict__ ln1b,
    const ushort* __restrict__ Winw, const float* __restrict__ Winb,
    const ushort* __restrict__ Woutw, const float* __restrict__ Woutb,
    const float* __restrict__ resw,
    const float* __restrict__ hVp,   // h_V' fp32
    float* __restrict__ outV,        // final h_V fp32 (d_out)
    ushort* __restrict__ hV2b) {     // final h_V bf16 copy (ws)

    __shared__ float  sHVp[16 * 132];
    __shared__ ushort sX[16 * 136];
    __shared__ ushort sY[16 * 520];
    __shared__ float  sMk[16];

    const int t = threadIdx.x;
    const int w = t >> 6;
    const int lane = t & 63;
    const int nb = blockIdx.x * 16;
    const int r16 = lane & 15, g4 = lane >> 4;

    #pragma unroll
    for (int i = 0; i < 8; i++) {
        int e = t + i * 256;
        sHVp[(e >> 7) * 132 + (e & 127)] = hVp[(size_t)nb * HH + e];
    }
    if (t < 16) sMk[t] = maskV[nb + t];
    __syncthreads();

    #pragma unroll
    for (int i = 0; i < 4; i++) {
        int row = w * 4 + i;
        float x0 = sHVp[row * 132 + lane], x1 = sHVp[row * 132 + 64 + lane];
        float s = wsum(x0 + x1);
        float q = wsum(x0 * x0 + x1 * x1);
        float mu = s * (1.0f / 128.0f);
        float rstd = rsqrtf(q * (1.0f / 128.0f) - mu * mu + 1e-5f);
        sX[row * 136 + lane]      = f2bf1((x0 - mu) * rstd * ln1g[lane]      + ln1b[lane]);
        sX[row * 136 + 64 + lane] = f2bf1((x1 - mu) * rstd * ln1g[64 + lane] + ln1b[64 + lane]);
    }
    __syncthreads();

    f32x4 acc1[8];
    #pragma unroll
    for (int nn = 0; nn < 8; nn++) acc1[nn] = (f32x4){0.f, 0.f, 0.f, 0.f};
    bf16x8 a1[4];
    #pragma unroll
    for (int kt = 0; kt < 4; kt++)
        a1[kt] = *(const bf16x8*)&sX[r16 * 136 + kt * 32 + g4 * 8];
    #pragma unroll
    for (int nn = 0; nn < 8; nn++) {
        const ushort* Wq = Winw + (w * 128 + nn * 16 + r16) * HH + g4 * 8;
        #pragma unroll
        for (int kt = 0; kt < 4; kt++)
            acc1[nn] = MFMA(a1[kt], *(const bf16x8*)(Wq + kt * 32), acc1[nn]);
    }
    #pragma unroll
    for (int nn = 0; nn < 8; nn++) {
        int col = w * 128 + nn * 16 + r16;
        float bb = Winb[col];
        #pragma unroll
        for (int r = 0; r < 4; r++)
            sY[(g4 * 4 + r) * 520 + col] = f2bf1(gelu_f(acc1[nn][r] + bb));
    }
    __syncthreads();

    f32x4 acc2[2];
    acc2[0] = (f32x4){0.f, 0.f, 0.f, 0.f};
    acc2[1] = (f32x4){0.f, 0.f, 0.f, 0.f};
    {
        const ushort* Wq = Woutw + (w * 32 + r16) * FF + g4 * 8;
        #pragma unroll 4
        for (int kt = 0; kt < 16; kt++) {
            bf16x8 a = *(const bf16x8*)&sY[r16 * 520 + kt * 32 + g4 * 8];
            acc2[0] = MFMA(a, *(const bf16x8*)(Wq + kt * 32), acc2[0]);
            acc2[1] = MFMA(a, *(const bf16x8*)(Wq + 16 * FF + kt * 32), acc2[1]);
        }
    }
    float rw = resw[0];
    #pragma unroll
    for (int nn = 0; nn < 2; nn++) {
        int col = w * 32 + nn * 16 + r16;
        float bb = Woutb[col];
        #pragma unroll
        for (int r = 0; r < 4; r++) {
            int row = g4 * 4 + r;
            float out = sHVp[row * 132 + col] + (acc2[nn][r] + bb) * rw;
            out *= sMk[row];
            outV[(size_t)(nb + row) * HH + col] = out;
            hV2b[(size_t)(nb + row) * HH + col] = f2bf1(out);
        }
    }
}

// ---------------- Kernel 4: edge update, 2 nodes/block (M=96) ----------------
// R8 structure + rawE bf16 copy in LDS: epilogue residual needs NO global re-read.
__global__ __launch_bounds__(256, 3) void k_edge(
    const float* __restrict__ hE, const int* __restrict__ Eidx,
    const ushort* __restrict__ W11w, const float* __restrict__ W11b,
    const ushort* __restrict__ W12w, const float* __restrict__ W12b,
    const ushort* __restrict__ W13w, const float* __restrict__ W13b,
    const float* __restrict__ ln2g, const float* __restrict__ ln2b,
    const ushort* __restrict__ hV2b,  // final h_V bf16
    float* __restrict__ outE) {

    __shared__ ushort buf[96 * ST];    // LN2(h_E) -> out1 -> out2 (in-place)
    __shared__ ushort rawE[96 * ST];   // bf16 copy of h_E (residual source)

    const int t = threadIdx.x;
    const int w = t >> 6;
    const int lane = t & 63;
    const int np = blockIdx.x * 2;
    const int b  = np >> 10;
    const size_t eb = (size_t)np * KK * EE;   // 96 contiguous edge rows
    const int r16 = lane & 15, g4 = lane >> 4;

    int myidx[6];
    #pragma unroll
    for (int mt = 0; mt < 6; mt++)
        myidx[mt] = Eidx[np * KK + mt * 16 + r16];

    // ---- LN2(h_E) -> buf ; raw bf16 -> rawE (hE read ONCE per block) ----
    {
        float g0 = ln2g[2 * lane], g1 = ln2g[2 * lane + 1];
        float c0 = ln2b[2 * lane], c1 = ln2b[2 * lane + 1];
        #pragma unroll 4
        for (int i = 0; i < 24; i++) {
            int k = w + i * 4;
            float2 pr = ((const float2*)(hE + eb + (size_t)k * EE))[lane];
            *(uint*)&rawE[k * ST + 2 * lane] = cvtpk(pr.x, pr.y);
            float x0 = pr.x, x1 = pr.y;
            float s = wsum(x0 + x1);
            float q = wsum(x0 * x0 + x1 * x1);
            float mu = s * (1.0f / 128.0f);
            float rstd = rsqrtf(q * (1.0f / 128.0f) - mu * mu + 1e-5f);
            uint packed = cvtpk((x0 - mu) * rstd * g0 + c0, (x1 - mu) * rstd * g1 + c1);
            *(uint*)&buf[k * ST + 2 * lane] = packed;
        }
    }
    __syncthreads();

    // ---- GEMM1 ----
    f32x4 acc[6][2];
    #pragma unroll
    for (int mt = 0; mt < 6; mt++) {
        acc[mt][0] = (f32x4){0.f, 0.f, 0.f, 0.f};
        acc[mt][1] = (f32x4){0.f, 0.f, 0.f, 0.f};
    }
    const ushort* Wp = W11w + (w * 32 + r16) * IN3 + g4 * 8;
    // neighbor gathers first (scattered)
    {
        const ushort* nb = hV2b + (size_t)b * NN * HH + g4 * 8;
        #pragma unroll
        for (int kt = 0; kt < 4; kt++) {
            bf16x8 b0 = *(const bf16x8*)(Wp + 256 + kt * 32);
            bf16x8 b1 = *(const bf16x8*)(Wp + 16 * IN3 + 256 + kt * 32);
            #pragma unroll
            for (int mt = 0; mt < 6; mt++) {
                bf16x8 a = *(const bf16x8*)(nb + (size_t)myidx[mt] * HH + kt * 32);
                acc[mt][0] = MFMA(a, b0, acc[mt][0]);
                acc[mt][1] = MFMA(a, b1, acc[mt][1]);
            }
        }
    }
    // LN2(h_E) from LDS
    #pragma unroll
    for (int kt = 0; kt < 4; kt++) {
        bf16x8 b0 = *(const bf16x8*)(Wp + 128 + kt * 32);
        bf16x8 b1 = *(const bf16x8*)(Wp + 16 * IN3 + 128 + kt * 32);
        #pragma unroll
        for (int mt = 0; mt < 6; mt++) {
            bf16x8 a = *(const bf16x8*)&buf[(mt * 16 + r16) * ST + kt * 32 + g4 * 8];
            acc[mt][0] = MFMA(a, b0, acc[mt][0]);
            acc[mt][1] = MFMA(a, b1, acc[mt][1]);
        }
    }
    // self h_V (two broadcast rows)
    {
        const ushort* sp0 = hV2b + (size_t)np * HH + g4 * 8;
        const ushort* sp1 = sp0 + HH;
        #pragma unroll
        for (int kt = 0; kt < 4; kt++) {
            bf16x8 a0 = *(const bf16x8*)(sp0 + kt * 32);
            bf16x8 a1s = *(const bf16x8*)(sp1 + kt * 32);
            bf16x8 b0 = *(const bf16x8*)(Wp + kt * 32);
            bf16x8 b1 = *(const bf16x8*)(Wp + 16 * IN3 + kt * 32);
            #pragma unroll
            for (int mt = 0; mt < 6; mt++) {
                bf16x8 a = (mt < 3) ? a0 : a1s;
                acc[mt][0] = MFMA(a, b0, acc[mt][0]);
                acc[mt][1] = MFMA(a, b1, acc[mt][1]);
            }
        }
    }
    __syncthreads();   // all reads of LN2 buf complete
    #pragma unroll
    for (int nn = 0; nn < 2; nn++) {
        int col = w * 32 + nn * 16 + r16;
        float bb = W11b[col];
        #pragma unroll
        for (int mt = 0; mt < 6; mt++)
            #pragma unroll
            for (int r = 0; r < 4; r++)
                buf[(mt * 16 + g4 * 4 + r) * ST + col] = f2bf1(gelu_f(acc[mt][nn][r] + bb));
    }
    __syncthreads();

    // ---- GEMM2 ----
    f32x4 acc2[6][2];
    #pragma unroll
    for (int mt = 0; mt < 6; mt++) {
        acc2[mt][0] = (f32x4){0.f, 0.f, 0.f, 0.f};
        acc2[mt][1] = (f32x4){0.f, 0.f, 0.f, 0.f};
    }
    {
        const ushort* Wp2 = W12w + (w * 32 + r16) * HH + g4 * 8;
        #pragma unroll
        for (int kt = 0; kt < 4; kt++) {
            bf16x8 b0 = *(const bf16x8*)(Wp2 + kt * 32);
            bf16x8 b1 = *(const bf16x8*)(Wp2 + 16 * HH + kt * 32);
            #pragma unroll
            for (int mt = 0; mt < 6; mt++) {
                bf16x8 a = *(const bf16x8*)&buf[(mt * 16 + r16) * ST + kt * 32 + g4 * 8];
                acc2[mt][0] = MFMA(a, b0, acc2[mt][0]);
                acc2[mt][1] = MFMA(a, b1, acc2[mt][1]);
            }
        }
    }
    __syncthreads();
    #pragma unroll
    for (int nn = 0; nn < 2; nn++) {
        int col = w * 32 + nn * 16 + r16;
        float bb = W12b[col];
        #pragma unroll
        for (int mt = 0; mt < 6; mt++)
            #pragma unroll
            for (int r = 0; r < 4; r++)
                buf[(mt * 16 + g4 * 4 + r) * ST + col] = f2bf1(gelu_f(acc2[mt][nn][r] + bb));
    }
    __syncthreads();

    // ---- GEMM3 -> residual from rawE (LDS) + direct store; NO global re-read ----
    f32x4 acc3[6][2];
    #pragma unroll
    for (int mt = 0; mt < 6; mt++) {
        acc3[mt][0] = (f32x4){0.f, 0.f, 0.f, 0.f};
        acc3[mt][1] = (f32x4){0.f, 0.f, 0.f, 0.f};
    }
    {
        const ushort* Wp3 = W13w + (w * 32 + r16) * HH + g4 * 8;
        #pragma unroll
        for (int kt = 0; kt < 4; kt++) {
            bf16x8 b0 = *(const bf16x8*)(Wp3 + kt * 32);
            bf16x8 b1 = *(const bf16x8*)(Wp3 + 16 * HH + kt * 32);
            #pragma unroll
            for (int mt = 0; mt < 6; mt++) {
                bf16x8 a = *(const bf16x8*)&buf[(mt * 16 + r16) * ST + kt * 32 + g4 * 8];
                acc3[mt][0] = MFMA(a, b0, acc3[mt][0]);
                acc3[mt][1] = MFMA(a, b1, acc3[mt][1]);
            }
        }
    }
    #pragma unroll
    for (int nn = 0; nn < 2; nn++) {
        int col = w * 32 + nn * 16 + r16;
        float bb = W13b[col];
        #pragma unroll
        for (int mt = 0; mt < 6; mt++)
            #pragma unroll
            for (int r = 0; r < 4; r++) {
                int row = mt * 16 + g4 * 4 + r;
                size_t off = eb + (size_t)row * EE + col;
                outE[off] = bf2f(rawE[row * ST + col]) + acc3[mt][nn][r] + bb;
            }
    }
}

extern "C" void kernel_launch(void* const* d_in, const int* in_sizes, int n_in,
                              void* d_out, int out_size, void* d_ws, size_t ws_size,
                              hipStream_t stream) {
    const float* hV      = (const float*)d_in[0];
    const float* hE      = (const float*)d_in[1];
    const int*   Eidx    = (const int*)d_in[2];
    const float* maskV   = (const float*)d_in[3];
    const float* maskAtt = (const float*)d_in[4];
    const float* W1w  = (const float*)d_in[5];
    const float* W1b  = (const float*)d_in[6];
    const float* W2w  = (const float*)d_in[7];
    const float* W2b  = (const float*)d_in[8];
    const float* W3w  = (const float*)d_in[9];
    const float* W3b  = (const float*)d_in[10];
    const float* W11w = (const float*)d_in[11];
    const float* W11b = (const float*)d_in[12];
    const float* W12w = (const float*)d_in[13];
    const float* W12b = (const float*)d_in[14];
    const float* W13w = (const float*)d_in[15];
    const float* W13b = (const float*)d_in[16];
    const float* ln0g = (const float*)d_in[17];
    const float* ln0b = (const float*)d_in[18];
    const float* ln1g = (const float*)d_in[19];
    const float* ln1b = (const float*)d_in[20];
    const float* ln2g = (const float*)d_in[21];
    const float* ln2b = (const float*)d_in[22];
    const float* Winw  = (const float*)d_in[23];
    const float* Winb  = (const float*)d_in[24];
    const float* Woutw = (const float*)d_in[25];
    const float* Woutb = (const float*)d_in[26];
    const float* resw  = (const float*)d_in[27];

    float* outV = (float*)d_out;
    float* outE = outV + (size_t)BB * NN * HH;

    // ws layout
    char* wsb = (char*)d_ws;
    ushort* wsHVn = (ushort*)wsb;                          // 1 MB bf16 LN0(h_V)
    float*  wHVp  = (float*)(wsb + (1 << 20));             // 2 MB fp32 h_V'
    ushort* wHV2b = (ushort*)(wsb + 3 * (1 << 20));        // 1 MB bf16 final h_V
    ushort* wW1   = (ushort*)(wsb + 4 * (1 << 20));
    ushort* wW2   = wW1  + HH * IN3;
    ushort* wW3   = wW2  + HH * HH;
    ushort* wW11  = wW3  + HH * HH;
    ushort* wW12  = wW11 + HH * IN3;
    ushort* wW13  = wW12 + HH * HH;
    ushort* wWin  = wW13 + HH * HH;
    ushort* wWout = wWin + FF * HH;

    k_cvt8<<<dim3(288), dim3(256), 0, stream>>>(
        W1w, W2w, W3w, W11w, W12w, W13w, Winw, Woutw,
        wW1, wW2, wW3, wW11, wW12, wW13, wWin, wWout);

    k_ln0<<<dim3(BB * NN / 4), dim3(256), 0, stream>>>(hV, ln0g, ln0b, wsHVn);
    k_node<<<dim3(BB * NN / 2), dim3(256), 0, stream>>>(
        hV, hE, Eidx, maskAtt,
        wW1, W1b, wW2, W2b, wW3, W3b, resw, wsHVn, wHVp);
    k_ffn<<<dim3(BB * NN / 16), dim3(256), 0, stream>>>(
        maskV, ln1g, ln1b, wWin, Winb, wWout, Woutb, resw, wHVp, outV, wHV2b);
    k_edge<<<dim3(BB * NN / 2), dim3(256), 0, stream>>>(
        hE, Eidx, wW11, W11b, wW12, W12b, wW13, W13b,
        ln2g, ln2b, wHV2b, outE);
}

// Round 15
// 233.503 us; speedup vs baseline: 1.3110x; 1.3110x over previous
//
#include <hip/hip_runtime.h>
#include <hip/hip_bf16.h>

#define BB 4
#define NN 1024
#define KK 48
#define HH 128
#define EE 128
#define IN3 384
#define FF 512
#define ST 132   // LDS row stride (ushorts)

typedef __attribute__((ext_vector_type(8))) short bf16x8;
typedef __attribute__((ext_vector_type(4))) float f32x4;

#define MFMA(a, b, c) __builtin_amdgcn_mfma_f32_16x16x32_bf16((a), (b), (c), 0, 0, 0)

__device__ __forceinline__ float bf2f(ushort u) {
    union { uint i; float f; } v; v.i = ((uint)u) << 16; return v.f;
}
__device__ __forceinline__ uint cvtpk(float a, float b) {
    uint r;
    asm("v_cvt_pk_bf16_f32 %0, %1, %2" : "=v"(r) : "v"(a), "v"(b));
    return r;
}
__device__ __forceinline__ ushort f2bf1(float v) {
    return (ushort)cvtpk(v, v);
}
__device__ __forceinline__ float wsum(float x) {
    #pragma unroll
    for (int o = 32; o; o >>= 1) x += __shfl_xor(x, o, 64);
    return x;
}
// tanh-form gelu: x*z/(z+1), z = exp2(2.3022061*(x + 0.044715 x^3))
__device__ __forceinline__ float gelu_f(float x) {
    float t = x * fmaf(x * x, 0.044715f, 1.0f);
    float a = fminf(t * 2.3022061f, 50.0f);
    float z;
    asm("v_exp_f32 %0, %1" : "=v"(z) : "v"(a));
    float r;
    asm("v_rcp_f32 %0, %1" : "=v"(r) : "v"(z + 1.0f));
    return x * z * r;
}

// ---------------- Kernel 0: all-weights fp32 -> bf16 (single launch) ----------------
__global__ __launch_bounds__(256) void k_cvt8(
    const float* __restrict__ s0, const float* __restrict__ s1,
    const float* __restrict__ s2, const float* __restrict__ s3,
    const float* __restrict__ s4, const float* __restrict__ s5,
    const float* __restrict__ s6, const float* __restrict__ s7,
    ushort* __restrict__ d0, ushort* __restrict__ d1,
    ushort* __restrict__ d2, ushort* __restrict__ d3,
    ushort* __restrict__ d4, ushort* __restrict__ d5,
    ushort* __restrict__ d6, ushort* __restrict__ d7) {
    int i = blockIdx.x * 256 + threadIdx.x;
    const float* s; ushort* d; int base;
    if      (i < 12288) { s = s0; d = d0; base = 0; }
    else if (i < 16384) { s = s1; d = d1; base = 12288; }
    else if (i < 20480) { s = s2; d = d2; base = 16384; }
    else if (i < 32768) { s = s3; d = d3; base = 20480; }
    else if (i < 36864) { s = s4; d = d4; base = 32768; }
    else if (i < 40960) { s = s5; d = d5; base = 36864; }
    else if (i < 57344) { s = s6; d = d6; base = 40960; }
    else                { s = s7; d = d7; base = 57344; }
    int j = i - base;
    float4 v = ((const float4*)s)[j];
    uint2 o;
    o.x = cvtpk(v.x, v.y);
    o.y = cvtpk(v.z, v.w);
    ((uint2*)d)[j] = o;
}

// ---------------- Kernel 1: LN0 over all nodes -> ws (bf16) ----------------
__global__ __launch_bounds__(256) void k_ln0(const float* __restrict__ hV,
                                             const float* __restrict__ g,
                                             const float* __restrict__ bta,
                                             ushort* __restrict__ out) {
    int row = blockIdx.x * 4 + (threadIdx.x >> 6);
    int l = threadIdx.x & 63;
    const float* src = hV + (size_t)row * HH;
    float x0 = src[l], x1 = src[l + 64];
    float s = wsum(x0 + x1);
    float q = wsum(x0 * x0 + x1 * x1);
    float mu = s * (1.0f / 128.0f);
    float rstd = rsqrtf(q * (1.0f / 128.0f) - mu * mu + 1e-5f);
    ushort* dst = out + (size_t)row * HH;
    dst[l]      = f2bf1((x0 - mu) * rstd * g[l]      + bta[l]);
    dst[l + 64] = f2bf1((x1 - mu) * rstd * g[l + 64] + bta[l + 64]);
}

// ---------------- Kernel 2: node message MLP, 2 nodes/block (M=96) ----------------
__global__ __launch_bounds__(256, 5) void k_node(
    const float* __restrict__ hV, const float* __restrict__ hE,
    const int* __restrict__ Eidx, const float* __restrict__ maskAtt,
    const ushort* __restrict__ W1w, const float* __restrict__ W1b,
    const ushort* __restrict__ W2w, const float* __restrict__ W2b,
    const ushort* __restrict__ W3w, const float* __restrict__ W3b,
    const float* __restrict__ resw,
    const ushort* __restrict__ hVn,   // LN0(h_V), bf16
    float* __restrict__ outHVp) {     // h_V' fp32

    __shared__ ushort buf[96 * ST];   // out1 / out2 (in-place with barriers)
    __shared__ float  sMask[96];
    __shared__ float  sCol[256];      // [2][128]

    const int t = threadIdx.x;
    const int w = t >> 6;
    const int lane = t & 63;
    const int np = blockIdx.x * 2;    // first node of the pair (b*N+n space)
    const int b  = np >> 10;
    const int r16 = lane & 15, g4 = lane >> 4;

    // edge indices for my 6 m-tiles (rows of the pair are contiguous: row = mt*16+r16)
    int myidx[6];
    #pragma unroll
    for (int mt = 0; mt < 6; mt++)
        myidx[mt] = Eidx[np * KK + mt * 16 + r16];
    if (t < 96) sMask[t] = maskAtt[np * KK + t];

    f32x4 acc[6][2];
    #pragma unroll
    for (int mt = 0; mt < 6; mt++) {
        acc[mt][0] = (f32x4){0.f, 0.f, 0.f, 0.f};
        acc[mt][1] = (f32x4){0.f, 0.f, 0.f, 0.f};
    }

    const ushort* Wp  = W1w + (w * 32 + r16) * IN3 + g4 * 8;
    const float*  hE0 = hE + (size_t)np * KK * EE;   // 96 contiguous rows

    // ---- GEMM1 section: h_E cols [128,256) (deepest latency first) ----
    #pragma unroll
    for (int kt = 0; kt < 4; kt++) {
        bf16x8 b0 = *(const bf16x8*)(Wp + 128 + kt * 32);
        bf16x8 b1 = *(const bf16x8*)(Wp + 16 * IN3 + 128 + kt * 32);
        #pragma unroll
        for (int mt = 0; mt < 6; mt++) {
            const float* p = hE0 + (size_t)(mt * 16 + r16) * EE + kt * 32 + g4 * 8;
            float4 f0 = *(const float4*)(p);
            float4 f1 = *(const float4*)(p + 4);
            union { uint u[4]; bf16x8 v; } a;
            a.u[0] = cvtpk(f0.x, f0.y); a.u[1] = cvtpk(f0.z, f0.w);
            a.u[2] = cvtpk(f1.x, f1.y); a.u[3] = cvtpk(f1.z, f1.w);
            acc[mt][0] = MFMA(a.v, b0, acc[mt][0]);
            acc[mt][1] = MFMA(a.v, b1, acc[mt][1]);
        }
    }
    // ---- GEMM1 section: neighbor LN0 cols [256,384) ----
    {
        const ushort* nb = hVn + (size_t)b * NN * HH + g4 * 8;
        #pragma unroll
        for (int kt = 0; kt < 4; kt++) {
            bf16x8 b0 = *(const bf16x8*)(Wp + 256 + kt * 32);
            bf16x8 b1 = *(const bf16x8*)(Wp + 16 * IN3 + 256 + kt * 32);
            #pragma unroll
            for (int mt = 0; mt < 6; mt++) {
                bf16x8 a = *(const bf16x8*)(nb + (size_t)myidx[mt] * HH + kt * 32);
                acc[mt][0] = MFMA(a, b0, acc[mt][0]);
                acc[mt][1] = MFMA(a, b1, acc[mt][1]);
            }
        }
    }
    // ---- GEMM1 section: self LN0 cols [0,128) (two broadcast rows) ----
    {
        const ushort* sp0 = hVn + (size_t)np * HH + g4 * 8;
        const ushort* sp1 = sp0 + HH;
        #pragma unroll
        for (int kt = 0; kt < 4; kt++) {
            bf16x8 a0 = *(const bf16x8*)(sp0 + kt * 32);
            bf16x8 a1 = *(const bf16x8*)(sp1 + kt * 32);
            bf16x8 b0 = *(const bf16x8*)(Wp + kt * 32);
            bf16x8 b1 = *(const bf16x8*)(Wp + 16 * IN3 + kt * 32);
            #pragma unroll
            for (int mt = 0; mt < 6; mt++) {
                bf16x8 a = (mt < 3) ? a0 : a1;
                acc[mt][0] = MFMA(a, b0, acc[mt][0]);
                acc[mt][1] = MFMA(a, b1, acc[mt][1]);
            }
        }
    }
    // bias + gelu -> buf (out1)
    #pragma unroll
    for (int nn = 0; nn < 2; nn++) {
        int col = w * 32 + nn * 16 + r16;
        float bb = W1b[col];
        #pragma unroll
        for (int mt = 0; mt < 6; mt++)
            #pragma unroll
            for (int r = 0; r < 4; r++)
                buf[(mt * 16 + g4 * 4 + r) * ST + col] = f2bf1(gelu_f(acc[mt][nn][r] + bb));
    }
    __syncthreads();

    // ---- GEMM2 ----
    f32x4 acc2[6][2];
    #pragma unroll
    for (int mt = 0; mt < 6; mt++) {
        acc2[mt][0] = (f32x4){0.f, 0.f, 0.f, 0.f};
        acc2[mt][1] = (f32x4){0.f, 0.f, 0.f, 0.f};
    }
    {
        const ushort* Wp2 = W2w + (w * 32 + r16) * HH + g4 * 8;
        #pragma unroll
        for (int kt = 0; kt < 4; kt++) {
            bf16x8 b0 = *(const bf16x8*)(Wp2 + kt * 32);
            bf16x8 b1 = *(const bf16x8*)(Wp2 + 16 * HH + kt * 32);
            #pragma unroll
            for (int mt = 0; mt < 6; mt++) {
                bf16x8 a = *(const bf16x8*)&buf[(mt * 16 + r16) * ST + kt * 32 + g4 * 8];
                acc2[mt][0] = MFMA(a, b0, acc2[mt][0]);
                acc2[mt][1] = MFMA(a, b1, acc2[mt][1]);
            }
        }
    }
    __syncthreads();   // all reads of out1 complete
    #pragma unroll
    for (int nn = 0; nn < 2; nn++) {
        int col = w * 32 + nn * 16 + r16;
        float bb = W2b[col];
        #pragma unroll
        for (int mt = 0; mt < 6; mt++)
            #pragma unroll
            for (int r = 0; r < 4; r++)
                buf[(mt * 16 + g4 * 4 + r) * ST + col] = f2bf1(gelu_f(acc2[mt][nn][r] + bb));
    }
    __syncthreads();

    // ---- GEMM3 + masked per-node column sum ----
    f32x4 acc3[6][2];
    #pragma unroll
    for (int mt = 0; mt < 6; mt++) {
        acc3[mt][0] = (f32x4){0.f, 0.f, 0.f, 0.f};
        acc3[mt][1] = (f32x4){0.f, 0.f, 0.f, 0.f};
    }
    {
        const ushort* Wp3 = W3w + (w * 32 + r16) * HH + g4 * 8;
        #pragma unroll
        for (int kt = 0; kt < 4; kt++) {
            bf16x8 b0 = *(const bf16x8*)(Wp3 + kt * 32);
            bf16x8 b1 = *(const bf16x8*)(Wp3 + 16 * HH + kt * 32);
            #pragma unroll
            for (int mt = 0; mt < 6; mt++) {
                bf16x8 a = *(const bf16x8*)&buf[(mt * 16 + r16) * ST + kt * 32 + g4 * 8];
                acc3[mt][0] = MFMA(a, b0, acc3[mt][0]);
                acc3[mt][1] = MFMA(a, b1, acc3[mt][1]);
            }
        }
    }
    {
        float b3a = W3b[w * 32 + r16];
        float b3b = W3b[w * 32 + 16 + r16];
        float s0a = 0.f, s0b = 0.f, s1a = 0.f, s1b = 0.f;
        #pragma unroll
        for (int mt = 0; mt < 6; mt++)
            #pragma unroll
            for (int r = 0; r < 4; r++) {
                int row = mt * 16 + g4 * 4 + r;
                float mk = sMask[row];
                float v0 = (acc3[mt][0][r] + b3a) * mk;
                float v1 = (acc3[mt][1][r] + b3b) * mk;
                if (mt < 3) { s0a += v0; s0b += v1; }
                else        { s1a += v0; s1b += v1; }
            }
        s0a += __shfl_xor(s0a, 16, 64); s0a += __shfl_xor(s0a, 32, 64);
        s0b += __shfl_xor(s0b, 16, 64); s0b += __shfl_xor(s0b, 32, 64);
        s1a += __shfl_xor(s1a, 16, 64); s1a += __shfl_xor(s1a, 32, 64);
        s1b += __shfl_xor(s1b, 16, 64); s1b += __shfl_xor(s1b, 32, 64);
        if (g4 == 0) {
            sCol[w * 32 + r16]            = s0a;
            sCol[w * 32 + 16 + r16]       = s0b;
            sCol[128 + w * 32 + r16]      = s1a;
            sCol[128 + w * 32 + 16 + r16] = s1b;
        }
    }
    __syncthreads();

    {
        float rw = resw[0];
        size_t o = (size_t)np * HH + t;    // t spans both nodes' 128 cols
        outHVp[o] = hV[o] + sCol[t] * (1.0f / 30.0f) * rw;
    }
}

// ---------------- Kernel 3: batched FFN (LN1 + Win/gelu/Wout, MFMA) ----------------
__global__ __launch_bounds__(256, 4) void k_ffn(
    const float* __restrict__ maskV,
    const float* __restrict__ ln1g, const float* __restrict__ ln1b,
    const ushort* __restrict__ Winw, const float* __restrict__ Winb,
    const ushort* __restrict__ Woutw, const float* __restrict__ Woutb,
    const float* __restrict__ resw,
    const float* __restrict__ hVp,   // h_V' fp32
    float* __restrict__ outV,        // final h_V fp32 (d_out)
    ushort* __restrict__ hV2b) {     // final h_V bf16 copy (ws)

    __shared__ float  sHVp[16 * 132];
    __shared__ ushort sX[16 * 136];
    __shared__ ushort sY[16 * 520];
    __shared__ float  sMk[16];

    const int t = threadIdx.x;
    const int w = t >> 6;
    const int lane = t & 63;
    const int nb = blockIdx.x * 16;
    const int r16 = lane & 15, g4 = lane >> 4;

    #pragma unroll
    for (int i = 0; i < 8; i++) {
        int e = t + i * 256;
        sHVp[(e >> 7) * 132 + (e & 127)] = hVp[(size_t)nb * HH + e];
    }
    if (t < 16) sMk[t] = maskV[nb + t];
    __syncthreads();

    #pragma unroll
    for (int i = 0; i < 4; i++) {
        int row = w * 4 + i;
        float x0 = sHVp[row * 132 + lane], x1 = sHVp[row * 132 + 64 + lane];
        float s = wsum(x0 + x1);
        float q = wsum(x0 * x0 + x1 * x1);
        float mu = s * (1.0f / 128.0f);
        float rstd = rsqrtf(q * (1.0f / 128.0f) - mu * mu + 1e-5f);
        sX[row * 136 + lane]      = f2bf1((x0 - mu) * rstd * ln1g[lane]      + ln1b[lane]);
        sX[row * 136 + 64 + lane] = f2bf1((x1 - mu) * rstd * ln1g[64 + lane] + ln1b[64 + lane]);
    }
    __syncthreads();

    f32x4 acc1[8];
    #pragma unroll
    for (int nn = 0; nn < 8; nn++) acc1[nn] = (f32x4){0.f, 0.f, 0.f, 0.f};
    bf16x8 a1[4];
    #pragma unroll
    for (int kt = 0; kt < 4; kt++)
        a1[kt] = *(const bf16x8*)&sX[r16 * 136 + kt * 32 + g4 * 8];
    #pragma unroll
    for (int nn = 0; nn < 8; nn++) {
        const ushort* Wq = Winw + (w * 128 + nn * 16 + r16) * HH + g4 * 8;
        #pragma unroll
        for (int kt = 0; kt < 4; kt++)
            acc1[nn] = MFMA(a1[kt], *(const bf16x8*)(Wq + kt * 32), acc1[nn]);
    }
    #pragma unroll
    for (int nn = 0; nn < 8; nn++) {
        int col = w * 128 + nn * 16 + r16;
        float bb = Winb[col];
        #pragma unroll
        for (int r = 0; r < 4; r++)
            sY[(g4 * 4 + r) * 520 + col] = f2bf1(gelu_f(acc1[nn][r] + bb));
    }
    __syncthreads();

    f32x4 acc2[2];
    acc2[0] = (f32x4){0.f, 0.f, 0.f, 0.f};
    acc2[1] = (f32x4){0.f, 0.f, 0.f, 0.f};
    {
        const ushort* Wq = Woutw + (w * 32 + r16) * FF + g4 * 8;
        #pragma unroll 4
        for (int kt = 0; kt < 16; kt++) {
            bf16x8 a = *(const bf16x8*)&sY[r16 * 520 + kt * 32 + g4 * 8];
            acc2[0] = MFMA(a, *(const bf16x8*)(Wq + kt * 32), acc2[0]);
            acc2[1] = MFMA(a, *(const bf16x8*)(Wq + 16 * FF + kt * 32), acc2[1]);
        }
    }
    float rw = resw[0];
    #pragma unroll
    for (int nn = 0; nn < 2; nn++) {
        int col = w * 32 + nn * 16 + r16;
        float bb = Woutb[col];
        #pragma unroll
        for (int r = 0; r < 4; r++) {
            int row = g4 * 4 + r;
            float out = sHVp[row * 132 + col] + (acc2[nn][r] + bb) * rw;
            out *= sMk[row];
            outV[(size_t)(nb + row) * HH + col] = out;
            hV2b[(size_t)(nb + row) * HH + col] = f2bf1(out);
        }
    }
}

// ---------------- Kernel 4: edge update, 2 nodes/block (M=96) ----------------
// R8 structure + rawE bf16 copy in LDS: epilogue residual needs NO global re-read.
__global__ __launch_bounds__(256, 3) void k_edge(
    const float* __restrict__ hE, const int* __restrict__ Eidx,
    const ushort* __restrict__ W11w, const float* __restrict__ W11b,
    const ushort* __restrict__ W12w, const float* __restrict__ W12b,
    const ushort* __restrict__ W13w, const float* __restrict__ W13b,
    const float* __restrict__ ln2g, const float* __restrict__ ln2b,
    const ushort* __restrict__ hV2b,  // final h_V bf16
    float* __restrict__ outE) {

    __shared__ ushort buf[96 * ST];    // LN2(h_E) -> out1 -> out2 (in-place)
    __shared__ ushort rawE[96 * ST];   // bf16 copy of h_E (residual source)

    const int t = threadIdx.x;
    const int w = t >> 6;
    const int lane = t & 63;
    const int np = blockIdx.x * 2;
    const int b  = np >> 10;
    const size_t eb = (size_t)np * KK * EE;   // 96 contiguous edge rows
    const int r16 = lane & 15, g4 = lane >> 4;

    int myidx[6];
    #pragma unroll
    for (int mt = 0; mt < 6; mt++)
        myidx[mt] = Eidx[np * KK + mt * 16 + r16];

    // ---- LN2(h_E) -> buf ; raw bf16 -> rawE (hE read ONCE per block) ----
    {
        float g0 = ln2g[2 * lane], g1 = ln2g[2 * lane + 1];
        float c0 = ln2b[2 * lane], c1 = ln2b[2 * lane + 1];
        #pragma unroll 4
        for (int i = 0; i < 24; i++) {
            int k = w + i * 4;
            float2 pr = ((const float2*)(hE + eb + (size_t)k * EE))[lane];
            *(uint*)&rawE[k * ST + 2 * lane] = cvtpk(pr.x, pr.y);
            float x0 = pr.x, x1 = pr.y;
            float s = wsum(x0 + x1);
            float q = wsum(x0 * x0 + x1 * x1);
            float mu = s * (1.0f / 128.0f);
            float rstd = rsqrtf(q * (1.0f / 128.0f) - mu * mu + 1e-5f);
            uint packed = cvtpk((x0 - mu) * rstd * g0 + c0, (x1 - mu) * rstd * g1 + c1);
            *(uint*)&buf[k * ST + 2 * lane] = packed;
        }
    }
    __syncthreads();

    // ---- GEMM1 ----
    f32x4 acc[6][2];
    #pragma unroll
    for (int mt = 0; mt < 6; mt++) {
        acc[mt][0] = (f32x4){0.f, 0.f, 0.f, 0.f};
        acc[mt][1] = (f32x4){0.f, 0.f, 0.f, 0.f};
    }
    const ushort* Wp = W11w + (w * 32 + r16) * IN3 + g4 * 8;
    // neighbor gathers first (scattered)
    {
        const ushort* nb = hV2b + (size_t)b * NN * HH + g4 * 8;
        #pragma unroll
        for (int kt = 0; kt < 4; kt++) {
            bf16x8 b0 = *(const bf16x8*)(Wp + 256 + kt * 32);
            bf16x8 b1 = *(const bf16x8*)(Wp + 16 * IN3 + 256 + kt * 32);
            #pragma unroll
            for (int mt = 0; mt < 6; mt++) {
                bf16x8 a = *(const bf16x8*)(nb + (size_t)myidx[mt] * HH + kt * 32);
                acc[mt][0] = MFMA(a, b0, acc[mt][0]);
                acc[mt][1] = MFMA(a, b1, acc[mt][1]);
            }
        }
    }
    // LN2(h_E) from LDS
    #pragma unroll
    for (int kt = 0; kt < 4; kt++) {
        bf16x8 b0 = *(const bf16x8*)(Wp + 128 + kt * 32);
        bf16x8 b1 = *(const bf16x8*)(Wp + 16 * IN3 + 128 + kt * 32);
        #pragma unroll
        for (int mt = 0; mt < 6; mt++) {
            bf16x8 a = *(const bf16x8*)&buf[(mt * 16 + r16) * ST + kt * 32 + g4 * 8];
            acc[mt][0] = MFMA(a, b0, acc[mt][0]);
            acc[mt][1] = MFMA(a, b1, acc[mt][1]);
        }
    }
    // self h_V (two broadcast rows)
    {
        const ushort* sp0 = hV2b + (size_t)np * HH + g4 * 8;
        const ushort* sp1 = sp0 + HH;
        #pragma unroll
        for (int kt = 0; kt < 4; kt++) {
            bf16x8 a0 = *(const bf16x8*)(sp0 + kt * 32);
            bf16x8 a1s = *(const bf16x8*)(sp1 + kt * 32);
            bf16x8 b0 = *(const bf16x8*)(Wp + kt * 32);
            bf16x8 b1 = *(const bf16x8*)(Wp + 16 * IN3 + kt * 32);
            #pragma unroll
            for (int mt = 0; mt < 6; mt++) {
                bf16x8 a = (mt < 3) ? a0 : a1s;
                acc[mt][0] = MFMA(a, b0, acc[mt][0]);
                acc[mt][1] = MFMA(a, b1, acc[mt][1]);
            }
        }
    }
    __syncthreads();   // all reads of LN2 buf complete
    #pragma unroll
    for (int nn = 0; nn < 2; nn++) {
        int col = w * 32 + nn * 16 + r16;
        float bb = W11b[col];
        #pragma unroll
        for (int mt = 0; mt < 6; mt++)
            #pragma unroll
            for (int r = 0; r < 4; r++)
                buf[(mt * 16 + g4 * 4 + r) * ST + col] = f2bf1(gelu_f(acc[mt][nn][r] + bb));
    }
    __syncthreads();

    // ---- GEMM2 ----
    f32x4 acc2[6][2];
    #pragma unroll
    for (int mt = 0; mt < 6; mt++) {
        acc2[mt][0] = (f32x4){0.f, 0.f, 0.f, 0.f};
        acc2[mt][1] = (f32x4){0.f, 0.f, 0.f, 0.f};
    }
    {
        const ushort* Wp2 = W12w + (w * 32 + r16) * HH + g4 * 8;
        #pragma unroll
        for (int kt = 0; kt < 4; kt++) {
            bf16x8 b0 = *(const bf16x8*)(Wp2 + kt * 32);
            bf16x8 b1 = *(const bf16x8*)(Wp2 + 16 * HH + kt * 32);
            #pragma unroll
            for (int mt = 0; mt < 6; mt++) {
                bf16x8 a = *(const bf16x8*)&buf[(mt * 16 + r16) * ST + kt * 32 + g4 * 8];
                acc2[mt][0] = MFMA(a, b0, acc2[mt][0]);
                acc2[mt][1] = MFMA(a, b1, acc2[mt][1]);
            }
        }
    }
    __syncthreads();
    #pragma unroll
    for (int nn = 0; nn < 2; nn++) {
        int col = w * 32 + nn * 16 + r16;
        float bb = W12b[col];
        #pragma unroll
        for (int mt = 0; mt < 6; mt++)
            #pragma unroll
            for (int r = 0; r < 4; r++)
                buf[(mt * 16 + g4 * 4 + r) * ST + col] = f2bf1(gelu_f(acc2[mt][nn][r] + bb));
    }
    __syncthreads();

    // ---- GEMM3 -> residual from rawE (LDS) + direct store; NO global re-read ----
    f32x4 acc3[6][2];
    #pragma unroll
    for (int mt = 0; mt < 6; mt++) {
        acc3[mt][0] = (f32x4){0.f, 0.f, 0.f, 0.f};
        acc3[mt][1] = (f32x4){0.f, 0.f, 0.f, 0.f};
    }
    {
        const ushort* Wp3 = W13w + (w * 32 + r16) * HH + g4 * 8;
        #pragma unroll
        for (int kt = 0; kt < 4; kt++) {
            bf16x8 b0 = *(const bf16x8*)(Wp3 + kt * 32);
            bf16x8 b1 = *(const bf16x8*)(Wp3 + 16 * HH + kt * 32);
            #pragma unroll
            for (int mt = 0; mt < 6; mt++) {
                bf16x8 a = *(const bf16x8*)&buf[(mt * 16 + r16) * ST + kt * 32 + g4 * 8];
                acc3[mt][0] = MFMA(a, b0, acc3[mt][0]);
                acc3[mt][1] = MFMA(a, b1, acc3[mt][1]);
            }
        }
    }
    #pragma unroll
    for (int nn = 0; nn < 2; nn++) {
        int col = w * 32 + nn * 16 + r16;
        float bb = W13b[col];
        #pragma unroll
        for (int mt = 0; mt < 6; mt++)
            #pragma unroll
            for (int r = 0; r < 4; r++) {
                int row = mt * 16 + g4 * 4 + r;
                size_t off = eb + (size_t)row * EE + col;
                outE[off] = bf2f(rawE[row * ST + col]) + acc3[mt][nn][r] + bb;
            }
    }
}

extern "C" void kernel_launch(void* const* d_in, const int* in_sizes, int n_in,
                              void* d_out, int out_size, void* d_ws, size_t ws_size,
                              hipStream_t stream) {
    const float* hV      = (const float*)d_in[0];
    const float* hE      = (const float*)d_in[1];
    const int*   Eidx    = (const int*)d_in[2];
    const float* maskV   = (const float*)d_in[3];
    const float* maskAtt = (const float*)d_in[4];
    const float* W1w  = (const float*)d_in[5];
    const float* W1b  = (const float*)d_in[6];
    const float* W2w  = (const float*)d_in[7];
    const float* W2b  = (const float*)d_in[8];
    const float* W3w  = (const float*)d_in[9];
    const float* W3b  = (const float*)d_in[10];
    const float* W11w = (const float*)d_in[11];
    const float* W11b = (const float*)d_in[12];
    const float* W12w = (const float*)d_in[13];
    const float* W12b = (const float*)d_in[14];
    const float* W13w = (const float*)d_in[15];
    const float* W13b = (const float*)d_in[16];
    const float* ln0g = (const float*)d_in[17];
    const float* ln0b = (const float*)d_in[18];
    const float* ln1g = (const float*)d_in[19];
    const float* ln1b = (const float*)d_in[20];
    const float* ln2g = (const float*)d_in[21];
    const float* ln2b = (const float*)d_in[22];
    const float* Winw  = (const float*)d_in[23];
    const float* Winb  = (const float*)d_in[24];
    const float* Woutw = (const float*)d_in[25];
    const float* Woutb = (const float*)d_in[26];
    const float* resw  = (const float*)d_in[27];

    float* outV = (float*)d_out;
    float* outE = outV + (size_t)BB * NN * HH;

    // ws layout
    char* wsb = (char*)d_ws;
    ushort* wsHVn = (ushort*)wsb;                          // 1 MB bf16 LN0(h_V)
    float*  wHVp  = (float*)(wsb + (1 << 20));             // 2 MB fp32 h_V'
    ushort* wHV2b = (ushort*)(wsb + 3 * (1 << 20));        // 1 MB bf16 final h_V
    ushort* wW1   = (ushort*)(wsb + 4 * (1 << 20));
    ushort* wW2   = wW1  + HH * IN3;
    ushort* wW3   = wW2  + HH * HH;
    ushort* wW11  = wW3  + HH * HH;
    ushort* wW12  = wW11 + HH * IN3;
    ushort* wW13  = wW12 + HH * HH;
    ushort* wWin  = wW13 + HH * HH;
    ushort* wWout = wWin + FF * HH;

    k_cvt8<<<dim3(288), dim3(256), 0, stream>>>(
        W1w, W2w, W3w, W11w, W12w, W13w, Winw, Woutw,
        wW1, wW2, wW3, wW11, wW12, wW13, wWin, wWout);

    k_ln0<<<dim3(BB * NN / 4), dim3(256), 0, stream>>>(hV, ln0g, ln0b, wsHVn);
    k_node<<<dim3(BB * NN / 2), dim3(256), 0, stream>>>(
        hV, hE, Eidx, maskAtt,
        wW1, W1b, wW2, W2b, wW3, W3b, resw, wsHVn, wHVp);
    k_ffn<<<dim3(BB * NN / 16), dim3(256), 0, stream>>>(
        maskV, ln1g, ln1b, wWin, Winb, wWout, Woutb, resw, wHVp, outV, wHV2b);
    k_edge<<<dim3(BB * NN / 2), dim3(256), 0, stream>>>(
        hE, Eidx, wW11, W11b, wW12, W12b, wW13, W13b,
        ln2g, ln2b, wHV2b, outE);
}

// Round 16
// 226.969 us; speedup vs baseline: 1.3488x; 1.0288x over previous
//
#include <hip/hip_runtime.h>
#include <hip/hip_bf16.h>

#define BB 4
#define NN 1024
#define KK 48
#define HH 128
#define EE 128
#define IN3 384
#define FF 512
#define ST 132   // LDS row stride (ushorts)

typedef __attribute__((ext_vector_type(8))) short bf16x8;
typedef __attribute__((ext_vector_type(4))) float f32x4;

#define MFMA(a, b, c) __builtin_amdgcn_mfma_f32_16x16x32_bf16((a), (b), (c), 0, 0, 0)

__device__ __forceinline__ float bf2f(ushort u) {
    union { uint i; float f; } v; v.i = ((uint)u) << 16; return v.f;
}
__device__ __forceinline__ uint cvtpk(float a, float b) {
    uint r;
    asm("v_cvt_pk_bf16_f32 %0, %1, %2" : "=v"(r) : "v"(a), "v"(b));
    return r;
}
__device__ __forceinline__ ushort f2bf1(float v) {
    return (ushort)cvtpk(v, v);
}
__device__ __forceinline__ float wsum(float x) {
    #pragma unroll
    for (int o = 32; o; o >>= 1) x += __shfl_xor(x, o, 64);
    return x;
}
// tanh-form gelu: x*z/(z+1), z = exp2(2.3022061*(x + 0.044715 x^3))
__device__ __forceinline__ float gelu_f(float x) {
    float t = x * fmaf(x * x, 0.044715f, 1.0f);
    float a = fminf(t * 2.3022061f, 50.0f);
    float z;
    asm("v_exp_f32 %0, %1" : "=v"(z) : "v"(a));
    float r;
    asm("v_rcp_f32 %0, %1" : "=v"(r) : "v"(z + 1.0f));
    return x * z * r;
}

// ---------------- Kernel 0: all-weights fp32 -> bf16 (single launch) ----------------
__global__ __launch_bounds__(256) void k_cvt8(
    const float* __restrict__ s0, const float* __restrict__ s1,
    const float* __restrict__ s2, const float* __restrict__ s3,
    const float* __restrict__ s4, const float* __restrict__ s5,
    const float* __restrict__ s6, const float* __restrict__ s7,
    ushort* __restrict__ d0, ushort* __restrict__ d1,
    ushort* __restrict__ d2, ushort* __restrict__ d3,
    ushort* __restrict__ d4, ushort* __restrict__ d5,
    ushort* __restrict__ d6, ushort* __restrict__ d7) {
    int i = blockIdx.x * 256 + threadIdx.x;
    const float* s; ushort* d; int base;
    if      (i < 12288) { s = s0; d = d0; base = 0; }
    else if (i < 16384) { s = s1; d = d1; base = 12288; }
    else if (i < 20480) { s = s2; d = d2; base = 16384; }
    else if (i < 32768) { s = s3; d = d3; base = 20480; }
    else if (i < 36864) { s = s4; d = d4; base = 32768; }
    else if (i < 40960) { s = s5; d = d5; base = 36864; }
    else if (i < 57344) { s = s6; d = d6; base = 40960; }
    else                { s = s7; d = d7; base = 57344; }
    int j = i - base;
    float4 v = ((const float4*)s)[j];
    uint2 o;
    o.x = cvtpk(v.x, v.y);
    o.y = cvtpk(v.z, v.w);
    ((uint2*)d)[j] = o;
}

// ---------------- Kernel 1: LN0 over all nodes -> ws (bf16) ----------------
__global__ __launch_bounds__(256) void k_ln0(const float* __restrict__ hV,
                                             const float* __restrict__ g,
                                             const float* __restrict__ bta,
                                             ushort* __restrict__ out) {
    int row = blockIdx.x * 4 + (threadIdx.x >> 6);
    int l = threadIdx.x & 63;
    const float* src = hV + (size_t)row * HH;
    float x0 = src[l], x1 = src[l + 64];
    float s = wsum(x0 + x1);
    float q = wsum(x0 * x0 + x1 * x1);
    float mu = s * (1.0f / 128.0f);
    float rstd = rsqrtf(q * (1.0f / 128.0f) - mu * mu + 1e-5f);
    ushort* dst = out + (size_t)row * HH;
    dst[l]      = f2bf1((x0 - mu) * rstd * g[l]      + bta[l]);
    dst[l + 64] = f2bf1((x1 - mu) * rstd * g[l + 64] + bta[l + 64]);
}

// ---------------- Kernel 2: node message MLP, 2 nodes/block (M=96) ----------------
__global__ __launch_bounds__(256, 4) void k_node(
    const float* __restrict__ hV, const float* __restrict__ hE,
    const int* __restrict__ Eidx, const float* __restrict__ maskAtt,
    const ushort* __restrict__ W1w, const float* __restrict__ W1b,
    const ushort* __restrict__ W2w, const float* __restrict__ W2b,
    const ushort* __restrict__ W3w, const float* __restrict__ W3b,
    const float* __restrict__ resw,
    const ushort* __restrict__ hVn,   // LN0(h_V), bf16
    float* __restrict__ outHVp) {     // h_V' fp32

    __shared__ ushort buf[96 * ST];   // out1 / out2 (in-place with barriers)
    __shared__ float  sMask[96];
    __shared__ float  sCol[256];      // [2][128]

    const int t = threadIdx.x;
    const int w = t >> 6;
    const int lane = t & 63;
    const int np = blockIdx.x * 2;    // first node of the pair (b*N+n space)
    const int b  = np >> 10;
    const int r16 = lane & 15, g4 = lane >> 4;

    // edge indices for my 6 m-tiles (rows of the pair are contiguous: row = mt*16+r16)
    int myidx[6];
    #pragma unroll
    for (int mt = 0; mt < 6; mt++)
        myidx[mt] = Eidx[np * KK + mt * 16 + r16];
    if (t < 96) sMask[t] = maskAtt[np * KK + t];

    f32x4 acc[6][2];
    #pragma unroll
    for (int mt = 0; mt < 6; mt++) {
        acc[mt][0] = (f32x4){0.f, 0.f, 0.f, 0.f};
        acc[mt][1] = (f32x4){0.f, 0.f, 0.f, 0.f};
    }

    const ushort* Wp  = W1w + (w * 32 + r16) * IN3 + g4 * 8;
    const float*  hE0 = hE + (size_t)np * KK * EE;   // 96 contiguous rows

    // ---- GEMM1 section: h_E cols [128,256) (deepest latency first) ----
    #pragma unroll
    for (int kt = 0; kt < 4; kt++) {
        bf16x8 b0 = *(const bf16x8*)(Wp + 128 + kt * 32);
        bf16x8 b1 = *(const bf16x8*)(Wp + 16 * IN3 + 128 + kt * 32);
        #pragma unroll
        for (int mt = 0; mt < 6; mt++) {
            const float* p = hE0 + (size_t)(mt * 16 + r16) * EE + kt * 32 + g4 * 8;
            float4 f0 = *(const float4*)(p);
            float4 f1 = *(const float4*)(p + 4);
            union { uint u[4]; bf16x8 v; } a;
            a.u[0] = cvtpk(f0.x, f0.y); a.u[1] = cvtpk(f0.z, f0.w);
            a.u[2] = cvtpk(f1.x, f1.y); a.u[3] = cvtpk(f1.z, f1.w);
            acc[mt][0] = MFMA(a.v, b0, acc[mt][0]);
            acc[mt][1] = MFMA(a.v, b1, acc[mt][1]);
        }
    }
    // ---- GEMM1 section: neighbor LN0 cols [256,384) ----
    {
        const ushort* nb = hVn + (size_t)b * NN * HH + g4 * 8;
        #pragma unroll
        for (int kt = 0; kt < 4; kt++) {
            bf16x8 b0 = *(const bf16x8*)(Wp + 256 + kt * 32);
            bf16x8 b1 = *(const bf16x8*)(Wp + 16 * IN3 + 256 + kt * 32);
            #pragma unroll
            for (int mt = 0; mt < 6; mt++) {
                bf16x8 a = *(const bf16x8*)(nb + (size_t)myidx[mt] * HH + kt * 32);
                acc[mt][0] = MFMA(a, b0, acc[mt][0]);
                acc[mt][1] = MFMA(a, b1, acc[mt][1]);
            }
        }
    }
    // ---- GEMM1 section: self LN0 cols [0,128) (two broadcast rows) ----
    {
        const ushort* sp0 = hVn + (size_t)np * HH + g4 * 8;
        const ushort* sp1 = sp0 + HH;
        #pragma unroll
        for (int kt = 0; kt < 4; kt++) {
            bf16x8 a0 = *(const bf16x8*)(sp0 + kt * 32);
            bf16x8 a1 = *(const bf16x8*)(sp1 + kt * 32);
            bf16x8 b0 = *(const bf16x8*)(Wp + kt * 32);
            bf16x8 b1 = *(const bf16x8*)(Wp + 16 * IN3 + kt * 32);
            #pragma unroll
            for (int mt = 0; mt < 6; mt++) {
                bf16x8 a = (mt < 3) ? a0 : a1;
                acc[mt][0] = MFMA(a, b0, acc[mt][0]);
                acc[mt][1] = MFMA(a, b1, acc[mt][1]);
            }
        }
    }
    // bias + gelu -> buf (out1)
    #pragma unroll
    for (int nn = 0; nn < 2; nn++) {
        int col = w * 32 + nn * 16 + r16;
        float bb = W1b[col];
        #pragma unroll
        for (int mt = 0; mt < 6; mt++)
            #pragma unroll
            for (int r = 0; r < 4; r++)
                buf[(mt * 16 + g4 * 4 + r) * ST + col] = f2bf1(gelu_f(acc[mt][nn][r] + bb));
    }
    __syncthreads();

    // ---- GEMM2 ----
    f32x4 acc2[6][2];
    #pragma unroll
    for (int mt = 0; mt < 6; mt++) {
        acc2[mt][0] = (f32x4){0.f, 0.f, 0.f, 0.f};
        acc2[mt][1] = (f32x4){0.f, 0.f, 0.f, 0.f};
    }
    {
        const ushort* Wp2 = W2w + (w * 32 + r16) * HH + g4 * 8;
        #pragma unroll
        for (int kt = 0; kt < 4; kt++) {
            bf16x8 b0 = *(const bf16x8*)(Wp2 + kt * 32);
            bf16x8 b1 = *(const bf16x8*)(Wp2 + 16 * HH + kt * 32);
            #pragma unroll
            for (int mt = 0; mt < 6; mt++) {
                bf16x8 a = *(const bf16x8*)&buf[(mt * 16 + r16) * ST + kt * 32 + g4 * 8];
                acc2[mt][0] = MFMA(a, b0, acc2[mt][0]);
                acc2[mt][1] = MFMA(a, b1, acc2[mt][1]);
            }
        }
    }
    __syncthreads();   // all reads of out1 complete
    #pragma unroll
    for (int nn = 0; nn < 2; nn++) {
        int col = w * 32 + nn * 16 + r16;
        float bb = W2b[col];
        #pragma unroll
        for (int mt = 0; mt < 6; mt++)
            #pragma unroll
            for (int r = 0; r < 4; r++)
                buf[(mt * 16 + g4 * 4 + r) * ST + col] = f2bf1(gelu_f(acc2[mt][nn][r] + bb));
    }
    __syncthreads();

    // ---- GEMM3 + masked per-node column sum ----
    f32x4 acc3[6][2];
    #pragma unroll
    for (int mt = 0; mt < 6; mt++) {
        acc3[mt][0] = (f32x4){0.f, 0.f, 0.f, 0.f};
        acc3[mt][1] = (f32x4){0.f, 0.f, 0.f, 0.f};
    }
    {
        const ushort* Wp3 = W3w + (w * 32 + r16) * HH + g4 * 8;
        #pragma unroll
        for (int kt = 0; kt < 4; kt++) {
            bf16x8 b0 = *(const bf16x8*)(Wp3 + kt * 32);
            bf16x8 b1 = *(const bf16x8*)(Wp3 + 16 * HH + kt * 32);
            #pragma unroll
            for (int mt = 0; mt < 6; mt++) {
                bf16x8 a = *(const bf16x8*)&buf[(mt * 16 + r16) * ST + kt * 32 + g4 * 8];
                acc3[mt][0] = MFMA(a, b0, acc3[mt][0]);
                acc3[mt][1] = MFMA(a, b1, acc3[mt][1]);
            }
        }
    }
    {
        float b3a = W3b[w * 32 + r16];
        float b3b = W3b[w * 32 + 16 + r16];
        float s0a = 0.f, s0b = 0.f, s1a = 0.f, s1b = 0.f;
        #pragma unroll
        for (int mt = 0; mt < 6; mt++)
            #pragma unroll
            for (int r = 0; r < 4; r++) {
                int row = mt * 16 + g4 * 4 + r;
                float mk = sMask[row];
                float v0 = (acc3[mt][0][r] + b3a) * mk;
                float v1 = (acc3[mt][1][r] + b3b) * mk;
                if (mt < 3) { s0a += v0; s0b += v1; }
                else        { s1a += v0; s1b += v1; }
            }
        s0a += __shfl_xor(s0a, 16, 64); s0a += __shfl_xor(s0a, 32, 64);
        s0b += __shfl_xor(s0b, 16, 64); s0b += __shfl_xor(s0b, 32, 64);
        s1a += __shfl_xor(s1a, 16, 64); s1a += __shfl_xor(s1a, 32, 64);
        s1b += __shfl_xor(s1b, 16, 64); s1b += __shfl_xor(s1b, 32, 64);
        if (g4 == 0) {
            sCol[w * 32 + r16]            = s0a;
            sCol[w * 32 + 16 + r16]       = s0b;
            sCol[128 + w * 32 + r16]      = s1a;
            sCol[128 + w * 32 + 16 + r16] = s1b;
        }
    }
    __syncthreads();

    {
        float rw = resw[0];
        size_t o = (size_t)np * HH + t;    // t spans both nodes' 128 cols
        outHVp[o] = hV[o] + sCol[t] * (1.0f / 30.0f) * rw;
    }
}

// ---------------- Kernel 3: batched FFN (LN1 + Win/gelu/Wout, MFMA) ----------------
__global__ __launch_bounds__(256, 4) void k_ffn(
    const float* __restrict__ maskV,
    const float* __restrict__ ln1g, const float* __restrict__ ln1b,
    const ushort* __restrict__ Winw, const float* __restrict__ Winb,
    const ushort* __restrict__ Woutw, const float* __restrict__ Woutb,
    const float* __restrict__ resw,
    const float* __restrict__ hVp,   // h_V' fp32
    float* __restrict__ outV,        // final h_V fp32 (d_out)
    ushort* __restrict__ hV2b) {     // final h_V bf16 copy (ws)

    __shared__ float  sHVp[16 * 132];
    __shared__ ushort sX[16 * 136];
    __shared__ ushort sY[16 * 520];
    __shared__ float  sMk[16];

    const int t = threadIdx.x;
    const int w = t >> 6;
    const int lane = t & 63;
    const int nb = blockIdx.x * 16;
    const int r16 = lane & 15, g4 = lane >> 4;

    #pragma unroll
    for (int i = 0; i < 8; i++) {
        int e = t + i * 256;
        sHVp[(e >> 7) * 132 + (e & 127)] = hVp[(size_t)nb * HH + e];
    }
    if (t < 16) sMk[t] = maskV[nb + t];
    __syncthreads();

    #pragma unroll
    for (int i = 0; i < 4; i++) {
        int row = w * 4 + i;
        float x0 = sHVp[row * 132 + lane], x1 = sHVp[row * 132 + 64 + lane];
        float s = wsum(x0 + x1);
        float q = wsum(x0 * x0 + x1 * x1);
        float mu = s * (1.0f / 128.0f);
        float rstd = rsqrtf(q * (1.0f / 128.0f) - mu * mu + 1e-5f);
        sX[row * 136 + lane]      = f2bf1((x0 - mu) * rstd * ln1g[lane]      + ln1b[lane]);
        sX[row * 136 + 64 + lane] = f2bf1((x1 - mu) * rstd * ln1g[64 + lane] + ln1b[64 + lane]);
    }
    __syncthreads();

    f32x4 acc1[8];
    #pragma unroll
    for (int nn = 0; nn < 8; nn++) acc1[nn] = (f32x4){0.f, 0.f, 0.f, 0.f};
    bf16x8 a1[4];
    #pragma unroll
    for (int kt = 0; kt < 4; kt++)
        a1[kt] = *(const bf16x8*)&sX[r16 * 136 + kt * 32 + g4 * 8];
    #pragma unroll
    for (int nn = 0; nn < 8; nn++) {
        const ushort* Wq = Winw + (w * 128 + nn * 16 + r16) * HH + g4 * 8;
        #pragma unroll
        for (int kt = 0; kt < 4; kt++)
            acc1[nn] = MFMA(a1[kt], *(const bf16x8*)(Wq + kt * 32), acc1[nn]);
    }
    #pragma unroll
    for (int nn = 0; nn < 8; nn++) {
        int col = w * 128 + nn * 16 + r16;
        float bb = Winb[col];
        #pragma unroll
        for (int r = 0; r < 4; r++)
            sY[(g4 * 4 + r) * 520 + col] = f2bf1(gelu_f(acc1[nn][r] + bb));
    }
    __syncthreads();

    f32x4 acc2[2];
    acc2[0] = (f32x4){0.f, 0.f, 0.f, 0.f};
    acc2[1] = (f32x4){0.f, 0.f, 0.f, 0.f};
    {
        const ushort* Wq = Woutw + (w * 32 + r16) * FF + g4 * 8;
        #pragma unroll 4
        for (int kt = 0; kt < 16; kt++) {
            bf16x8 a = *(const bf16x8*)&sY[r16 * 520 + kt * 32 + g4 * 8];
            acc2[0] = MFMA(a, *(const bf16x8*)(Wq + kt * 32), acc2[0]);
            acc2[1] = MFMA(a, *(const bf16x8*)(Wq + 16 * FF + kt * 32), acc2[1]);
        }
    }
    float rw = resw[0];
    #pragma unroll
    for (int nn = 0; nn < 2; nn++) {
        int col = w * 32 + nn * 16 + r16;
        float bb = Woutb[col];
        #pragma unroll
        for (int r = 0; r < 4; r++) {
            int row = g4 * 4 + r;
            float out = sHVp[row * 132 + col] + (acc2[nn][r] + bb) * rw;
            out *= sMk[row];
            outV[(size_t)(nb + row) * HH + col] = out;
            hV2b[(size_t)(nb + row) * HH + col] = f2bf1(out);
        }
    }
}

// ---------------- Kernel 4: edge update, 2 nodes/block (M=96) ----------------
// R8 structure + rawE bf16 copy in LDS: epilogue residual needs NO global re-read.
__global__ __launch_bounds__(256, 3) void k_edge(
    const float* __restrict__ hE, const int* __restrict__ Eidx,
    const ushort* __restrict__ W11w, const float* __restrict__ W11b,
    const ushort* __restrict__ W12w, const float* __restrict__ W12b,
    const ushort* __restrict__ W13w, const float* __restrict__ W13b,
    const float* __restrict__ ln2g, const float* __restrict__ ln2b,
    const ushort* __restrict__ hV2b,  // final h_V bf16
    float* __restrict__ outE) {

    __shared__ ushort buf[96 * ST];    // LN2(h_E) -> out1 -> out2 (in-place)
    __shared__ ushort rawE[96 * ST];   // bf16 copy of h_E (residual source)

    const int t = threadIdx.x;
    const int w = t >> 6;
    const int lane = t & 63;
    const int np = blockIdx.x * 2;
    const int b  = np >> 10;
    const size_t eb = (size_t)np * KK * EE;   // 96 contiguous edge rows
    const int r16 = lane & 15, g4 = lane >> 4;

    int myidx[6];
    #pragma unroll
    for (int mt = 0; mt < 6; mt++)
        myidx[mt] = Eidx[np * KK + mt * 16 + r16];

    // ---- LN2(h_E) -> buf ; raw bf16 -> rawE (hE read ONCE per block) ----
    {
        float g0 = ln2g[2 * lane], g1 = ln2g[2 * lane + 1];
        float c0 = ln2b[2 * lane], c1 = ln2b[2 * lane + 1];
        #pragma unroll 4
        for (int i = 0; i < 24; i++) {
            int k = w + i * 4;
            float2 pr = ((const float2*)(hE + eb + (size_t)k * EE))[lane];
            *(uint*)&rawE[k * ST + 2 * lane] = cvtpk(pr.x, pr.y);
            float x0 = pr.x, x1 = pr.y;
            float s = wsum(x0 + x1);
            float q = wsum(x0 * x0 + x1 * x1);
            float mu = s * (1.0f / 128.0f);
            float rstd = rsqrtf(q * (1.0f / 128.0f) - mu * mu + 1e-5f);
            uint packed = cvtpk((x0 - mu) * rstd * g0 + c0, (x1 - mu) * rstd * g1 + c1);
            *(uint*)&buf[k * ST + 2 * lane] = packed;
        }
    }
    __syncthreads();

    // ---- GEMM1 ----
    f32x4 acc[6][2];
    #pragma unroll
    for (int mt = 0; mt < 6; mt++) {
        acc[mt][0] = (f32x4){0.f, 0.f, 0.f, 0.f};
        acc[mt][1] = (f32x4){0.f, 0.f, 0.f, 0.f};
    }
    const ushort* Wp = W11w + (w * 32 + r16) * IN3 + g4 * 8;
    // neighbor gathers first (scattered)
    {
        const ushort* nb = hV2b + (size_t)b * NN * HH + g4 * 8;
        #pragma unroll
        for (int kt = 0; kt < 4; kt++) {
            bf16x8 b0 = *(const bf16x8*)(Wp + 256 + kt * 32);
            bf16x8 b1 = *(const bf16x8*)(Wp + 16 * IN3 + 256 + kt * 32);
            #pragma unroll
            for (int mt = 0; mt < 6; mt++) {
                bf16x8 a = *(const bf16x8*)(nb + (size_t)myidx[mt] * HH + kt * 32);
                acc[mt][0] = MFMA(a, b0, acc[mt][0]);
                acc[mt][1] = MFMA(a, b1, acc[mt][1]);
            }
        }
    }
    // LN2(h_E) from LDS
    #pragma unroll
    for (int kt = 0; kt < 4; kt++) {
        bf16x8 b0 = *(const bf16x8*)(Wp + 128 + kt * 32);
        bf16x8 b1 = *(const bf16x8*)(Wp + 16 * IN3 + 128 + kt * 32);
        #pragma unroll
        for (int mt = 0; mt < 6; mt++) {
            bf16x8 a = *(const bf16x8*)&buf[(mt * 16 + r16) * ST + kt * 32 + g4 * 8];
            acc[mt][0] = MFMA(a, b0, acc[mt][0]);
            acc[mt][1] = MFMA(a, b1, acc[mt][1]);
        }
    }
    // self h_V (two broadcast rows)
    {
        const ushort* sp0 = hV2b + (size_t)np * HH + g4 * 8;
        const ushort* sp1 = sp0 + HH;
        #pragma unroll
        for (int kt = 0; kt < 4; kt++) {
            bf16x8 a0 = *(const bf16x8*)(sp0 + kt * 32);
            bf16x8 a1s = *(const bf16x8*)(sp1 + kt * 32);
            bf16x8 b0 = *(const bf16x8*)(Wp + kt * 32);
            bf16x8 b1 = *(const bf16x8*)(Wp + 16 * IN3 + kt * 32);
            #pragma unroll
            for (int mt = 0; mt < 6; mt++) {
                bf16x8 a = (mt < 3) ? a0 : a1s;
                acc[mt][0] = MFMA(a, b0, acc[mt][0]);
                acc[mt][1] = MFMA(a, b1, acc[mt][1]);
            }
        }
    }
    __syncthreads();   // all reads of LN2 buf complete
    #pragma unroll
    for (int nn = 0; nn < 2; nn++) {
        int col = w * 32 + nn * 16 + r16;
        float bb = W11b[col];
        #pragma unroll
        for (int mt = 0; mt < 6; mt++)
            #pragma unroll
            for (int r = 0; r < 4; r++)
                buf[(mt * 16 + g4 * 4 + r) * ST + col] = f2bf1(gelu_f(acc[mt][nn][r] + bb));
    }
    __syncthreads();

    // ---- GEMM2 ----
    f32x4 acc2[6][2];
    #pragma unroll
    for (int mt = 0; mt < 6; mt++) {
        acc2[mt][0] = (f32x4){0.f, 0.f, 0.f, 0.f};
        acc2[mt][1] = (f32x4){0.f, 0.f, 0.f, 0.f};
    }
    {
        const ushort* Wp2 = W12w + (w * 32 + r16) * HH + g4 * 8;
        #pragma unroll
        for (int kt = 0; kt < 4; kt++) {
            bf16x8 b0 = *(const bf16x8*)(Wp2 + kt * 32);
            bf16x8 b1 = *(const bf16x8*)(Wp2 + 16 * HH + kt * 32);
            #pragma unroll
            for (int mt = 0; mt < 6; mt++) {
                bf16x8 a = *(const bf16x8*)&buf[(mt * 16 + r16) * ST + kt * 32 + g4 * 8];
                acc2[mt][0] = MFMA(a, b0, acc2[mt][0]);
                acc2[mt][1] = MFMA(a, b1, acc2[mt][1]);
            }
        }
    }
    __syncthreads();
    #pragma unroll
    for (int nn = 0; nn < 2; nn++) {
        int col = w * 32 + nn * 16 + r16;
        float bb = W12b[col];
        #pragma unroll
        for (int mt = 0; mt < 6; mt++)
            #pragma unroll
            for (int r = 0; r < 4; r++)
                buf[(mt * 16 + g4 * 4 + r) * ST + col] = f2bf1(gelu_f(acc2[mt][nn][r] + bb));
    }
    __syncthreads();

    // ---- GEMM3 -> residual from rawE (LDS) + direct store; NO global re-read ----
    f32x4 acc3[6][2];
    #pragma unroll
    for (int mt = 0; mt < 6; mt++) {
        acc3[mt][0] = (f32x4){0.f, 0.f, 0.f, 0.f};
        acc3[mt][1] = (f32x4){0.f, 0.f, 0.f, 0.f};
    }
    {
        const ushort* Wp3 = W13w + (w * 32 + r16) * HH + g4 * 8;
        #pragma unroll
        for (int kt = 0; kt < 4; kt++) {
            bf16x8 b0 = *(const bf16x8*)(Wp3 + kt * 32);
            bf16x8 b1 = *(const bf16x8*)(Wp3 + 16 * HH + kt * 32);
            #pragma unroll
            for (int mt = 0; mt < 6; mt++) {
                bf16x8 a = *(const bf16x8*)&buf[(mt * 16 + r16) * ST + kt * 32 + g4 * 8];
                acc3[mt][0] = MFMA(a, b0, acc3[mt][0]);
                acc3[mt][1] = MFMA(a, b1, acc3[mt][1]);
            }
        }
    }
    #pragma unroll
    for (int nn = 0; nn < 2; nn++) {
        int col = w * 32 + nn * 16 + r16;
        float bb = W13b[col];
        #pragma unroll
        for (int mt = 0; mt < 6; mt++)
            #pragma unroll
            for (int r = 0; r < 4; r++) {
                int row = mt * 16 + g4 * 4 + r;
                size_t off = eb + (size_t)row * EE + col;
                outE[off] = bf2f(rawE[row * ST + col]) + acc3[mt][nn][r] + bb;
            }
    }
}

extern "C" void kernel_launch(void* const* d_in, const int* in_sizes, int n_in,
                              void* d_out, int out_size, void* d_ws, size_t ws_size,
                              hipStream_t stream) {
    const float* hV      = (const float*)d_in[0];
    const float* hE      = (const float*)d_in[1];
    const int*   Eidx    = (const int*)d_in[2];
    const float* maskV   = (const float*)d_in[3];
    const float* maskAtt = (const float*)d_in[4];
    const float* W1w  = (const float*)d_in[5];
    const float* W1b  = (const float*)d_in[6];
    const float* W2w  = (const float*)d_in[7];
    const float* W2b  = (const float*)d_in[8];
    const float* W3w  = (const float*)d_in[9];
    const float* W3b  = (const float*)d_in[10];
    const float* W11w = (const float*)d_in[11];
    const float* W11b = (const float*)d_in[12];
    const float* W12w = (const float*)d_in[13];
    const float* W12b = (const float*)d_in[14];
    const float* W13w = (const float*)d_in[15];
    const float* W13b = (const float*)d_in[16];
    const float* ln0g = (const float*)d_in[17];
    const float* ln0b = (const float*)d_in[18];
    const float* ln1g = (const float*)d_in[19];
    const float* ln1b = (const float*)d_in[20];
    const float* ln2g = (const float*)d_in[21];
    const float* ln2b = (const float*)d_in[22];
    const float* Winw  = (const float*)d_in[23];
    const float* Winb  = (const float*)d_in[24];
    const float* Woutw = (const float*)d_in[25];
    const float* Woutb = (const float*)d_in[26];
    const float* resw  = (const float*)d_in[27];

    float* outV = (float*)d_out;
    float* outE = outV + (size_t)BB * NN * HH;

    // ws layout
    char* wsb = (char*)d_ws;
    ushort* wsHVn = (ushort*)wsb;                          // 1 MB bf16 LN0(h_V)
    float*  wHVp  = (float*)(wsb + (1 << 20));             // 2 MB fp32 h_V'
    ushort* wHV2b = (ushort*)(wsb + 3 * (1 << 20));        // 1 MB bf16 final h_V
    ushort* wW1   = (ushort*)(wsb + 4 * (1 << 20));
    ushort* wW2   = wW1  + HH * IN3;
    ushort* wW3   = wW2  + HH * HH;
    ushort* wW11  = wW3  + HH * HH;
    ushort* wW12  = wW11 + HH * IN3;
    ushort* wW13  = wW12 + HH * HH;
    ushort* wWin  = wW13 + HH * HH;
    ushort* wWout = wWin + FF * HH;

    k_cvt8<<<dim3(288), dim3(256), 0, stream>>>(
        W1w, W2w, W3w, W11w, W12w, W13w, Winw, Woutw,
        wW1, wW2, wW3, wW11, wW12, wW13, wWin, wWout);

    k_ln0<<<dim3(BB * NN / 4), dim3(256), 0, stream>>>(hV, ln0g, ln0b, wsHVn);
    k_node<<<dim3(BB * NN / 2), dim3(256), 0, stream>>>(
        hV, hE, Eidx, maskAtt,
        wW1, W1b, wW2, W2b, wW3, W3b, resw, wsHVn, wHVp);
    k_ffn<<<dim3(BB * NN / 16), dim3(256), 0, stream>>>(
        maskV, ln1g, ln1b, wWin, Winb, wWout, Woutb, resw, wHVp, outV, wHV2b);
    k_edge<<<dim3(BB * NN / 2), dim3(256), 0, stream>>>(
        hE, Eidx, wW11, W11b, wW12, W12b, wW13, W13b,
        ln2g, ln2b, wHV2b, outE);
}